// Round 7
// baseline (647.624 us; speedup 1.0000x reference)
//
#include <hip/hip_runtime.h>
#include <hip/hip_bf16.h>
#include <math.h>

#define N_NODES 50000
#define N_EDGES 800000
#define HID 64
#define N_CHUNKS ((N_NODES + 255) / 256)   // 196
#define QKVS_TILE 64
#define N_QKVS_BLOCKS ((N_NODES + QKVS_TILE - 1) / QKVS_TILE)  // 782

__device__ __forceinline__ unsigned short f32_to_bf16_rne(float f) {
    unsigned int u = __float_as_uint(f);
    unsigned int r = u + 0x7fffu + ((u >> 16) & 1u);
    return (unsigned short)(r >> 16);
}

// readlane on a float MUST bit-cast: __builtin_amdgcn_readlane is int(int,int)
// and passing a float does a VALUE conversion (R5 bug: absmax 1.03).
__device__ __forceinline__ float readlane_f32(float v, int i) {
    return __int_as_float(__builtin_amdgcn_readlane(__float_as_int(v), i));
}

// ---------------------------------------------------------------------------
// Kernel 1: initial LayerNorm over 32 features. One 32-lane half-wave per node.
__global__ void ln0_kernel(const float* __restrict__ x,
                           const float* __restrict__ g,
                           const float* __restrict__ b,
                           float* __restrict__ h0) {
    int lane = threadIdx.x & 63;
    int n = blockIdx.x * 8 + (threadIdx.x >> 6) * 2 + (lane >> 5);
    int c = lane & 31;
    float v = x[n * 32 + c];
    float s = v;
    #pragma unroll
    for (int off = 1; off < 32; off <<= 1) s += __shfl_xor(s, off);
    float mu = s * (1.0f / 32.0f);
    float d = v - mu;
    float vs = d * d;
    #pragma unroll
    for (int off = 1; off < 32; off <<= 1) vs += __shfl_xor(vs, off);
    float var = vs * (1.0f / 32.0f);
    float y = d * rsqrtf(var + 1e-5f) * g[c] + b[c];
    h0[n * 32 + c] = y;
}

// ---------------------------------------------------------------------------
// CSR build: zero, degree count, 3-phase hierarchical scan, scatter fill.
__global__ void zero_deg_kernel(int* __restrict__ deg) {
    int i = blockIdx.x * 256 + threadIdx.x;
    if (i < N_NODES) deg[i] = 0;
}

__global__ void deg_kernel(const int* __restrict__ dst, int* __restrict__ deg) {
    int e = blockIdx.x * blockDim.x + threadIdx.x;
    if (e >= N_EDGES) return;
    atomicAdd(&deg[dst[e]], 1);
}

__global__ void chunk_sum_kernel(const int* __restrict__ deg, int* __restrict__ csum) {
    int i = blockIdx.x * 256 + threadIdx.x;
    int v = (i < N_NODES) ? deg[i] : 0;
    #pragma unroll
    for (int off = 1; off < 64; off <<= 1) v += __shfl_xor(v, off);
    __shared__ int ws[4];
    if ((threadIdx.x & 63) == 0) ws[threadIdx.x >> 6] = v;
    __syncthreads();
    if (threadIdx.x == 0) csum[blockIdx.x] = ws[0] + ws[1] + ws[2] + ws[3];
}

__global__ void scan_sums_kernel(const int* __restrict__ csum,
                                 int* __restrict__ coff,
                                 int* __restrict__ row_ptr) {
    int lane = threadIdx.x;
    int carry = 0;
    for (int base = 0; base < N_CHUNKS; base += 64) {
        int i = base + lane;
        int v = (i < N_CHUNKS) ? csum[i] : 0;
        int incl = v;
        #pragma unroll
        for (int off = 1; off < 64; off <<= 1) {
            int t = __shfl_up(incl, off);
            if (lane >= off) incl += t;
        }
        if (i < N_CHUNKS) coff[i] = carry + incl - v;
        carry += __shfl(incl, 63);
    }
    if (lane == 0) row_ptr[N_NODES] = carry;
}

__global__ void scan_final_kernel(const int* __restrict__ deg,
                                  const int* __restrict__ coff,
                                  int* __restrict__ row_ptr,
                                  int* __restrict__ cursor) {
    int i = blockIdx.x * 256 + threadIdx.x;
    int lane = threadIdx.x & 63;
    int w = threadIdx.x >> 6;
    int v = (i < N_NODES) ? deg[i] : 0;
    int incl = v;
    #pragma unroll
    for (int off = 1; off < 64; off <<= 1) {
        int t = __shfl_up(incl, off);
        if (lane >= off) incl += t;
    }
    __shared__ int ws[4];
    if (lane == 63) ws[w] = incl;
    __syncthreads();
    int woff = 0;
    #pragma unroll
    for (int k = 0; k < 4; k++) if (k < w) woff += ws[k];
    int excl = coff[blockIdx.x] + woff + incl - v;
    if (i < N_NODES) { row_ptr[i] = excl; cursor[i] = excl; }
}

__global__ void fill_kernel(const int* __restrict__ src,
                            const int* __restrict__ dst,
                            int* __restrict__ cursor,
                            int* __restrict__ colb) {
    int e = blockIdx.x * blockDim.x + threadIdx.x;
    if (e >= N_EDGES) return;
    int d = dst[e];
    int pos = atomicAdd(&cursor[d], 1);
    colb[pos] = src[e];
}

// ---------------------------------------------------------------------------
// Kernel: Q/K/V/Skip projections, register-blocked skinny GEMM, no LDS.
// Wave holds h rows in VGPRs (lane = channel) and broadcasts via readlane
// (bit-cast!); thread (which,j) keeps its 64-entry weight column in VGPRs.
// K,V written bf16-packed: KV[n*64+c] = (bf16(V)<<16) | bf16(K).
template <int D>
__global__ __launch_bounds__(256) void qkvs_kernel(
                            const float* __restrict__ h,
                            const float* __restrict__ Wq, const float* __restrict__ bq,
                            const float* __restrict__ Wk, const float* __restrict__ bk,
                            const float* __restrict__ Wv, const float* __restrict__ bv,
                            const float* __restrict__ Ws,
                            float* __restrict__ Q, unsigned int* __restrict__ KV,
                            float* __restrict__ S) {
    int t = threadIdx.x;
    int lane = t & 63;
    int which = t >> 6;
    int j = lane;
    int n0 = blockIdx.x * QKVS_TILE;
    int cnt = min(QKVS_TILE, N_NODES - n0);   // 64, or 16 in last block (both %8==0)

    const float* W    = (which == 0) ? Wq : (which == 1) ? Wk : (which == 2) ? Wv : Ws;
    const float* bias = (which == 0) ? bq : (which == 1) ? bk : (which == 2) ? bv : nullptr;

    float wcol[D];
    #pragma unroll
    for (int i = 0; i < D; i++) wcol[i] = W[i * 64 + j];
    float bj = (which == 3) ? 0.0f : bias[j];

    unsigned short* KVus = (unsigned short*)KV;

    for (int nc = 0; nc < cnt; nc += 8) {
        float hreg[8];
        #pragma unroll
        for (int r = 0; r < 8; r++)
            hreg[r] = h[(n0 + nc + r) * D + (lane & (D - 1))];

        float acc[8];
        #pragma unroll
        for (int r = 0; r < 8; r++) acc[r] = bj;
        #pragma unroll
        for (int i = 0; i < D; i++) {
            #pragma unroll
            for (int r = 0; r < 8; r++)
                acc[r] = fmaf(readlane_f32(hreg[r], i), wcol[i], acc[r]);
        }

        #pragma unroll
        for (int r = 0; r < 8; r++) {
            int node = n0 + nc + r;
            if (which == 1 || which == 2) {
                KVus[(node * 64 + j) * 2 + (which - 1)] = f32_to_bf16_rne(acc[r]);
            } else {
                float* out = (which == 0) ? Q : S;
                out[node * 64 + j] = acc[r];
            }
        }
    }
}

// ---------------------------------------------------------------------------
// Kernel: per-node attention aggregation + skip + LayerNorm (+res/relu).
// One wave per node, split into 4 groups of 16 lanes; each group streams its
// own quarter of the edge list; each lane covers 4 packed-bf16 channels so a
// group's uint4 load fetches a whole 256 B KV row (1 VMEM inst / 4 edges).
// No max-subtraction (scores O(3), exp fp32-safe; identical to ref softmax).
template <int HEADS, bool RES, bool RELU>
__global__ __launch_bounds__(256) void agg_kernel(
                           const float* __restrict__ Q, const unsigned int* __restrict__ KV,
                           const float* __restrict__ S,
                           const int* __restrict__ row_ptr, const int* __restrict__ colb,
                           const float* __restrict__ g, const float* __restrict__ b,
                           const float* __restrict__ h_in, float* __restrict__ h_out) {
    constexpr int C = HID / HEADS;
    int lane = threadIdx.x & 63;
    int m = lane & 15;      // sub-lane: channels 4m..4m+3, head = m*4/C
    int grp = lane >> 4;    // edge group 0..3
    int n = blockIdx.x * 4 + (threadIdx.x >> 6);

    const float scale = rsqrtf((float)C);
    float4 q4 = *(const float4*)&Q[n * 64 + 4 * m];
    q4.x *= scale; q4.y *= scale; q4.z *= scale; q4.w *= scale;

    int beg = row_ptr[n], end = row_ptr[n + 1];

    float ssum = 0.0f;
    float acc0 = 0.0f, acc1 = 0.0f, acc2 = 0.0f, acc3 = 0.0f;

    for (int base = beg; base < end; base += 64) {
        int limit = end - base;
        int src_l = (base + lane < end) ? colb[base + lane] : 0;
        int iters = (min(limit, 64) + 3) >> 2;
        #pragma unroll 4
        for (int jj = 0; jj < iters; jj++) {
            int esl = jj * 4 + grp;                  // edge slot in this chunk
            int src = __shfl(src_l, esl);            // ds_bpermute broadcast
            uint4 kv = *(const uint4*)&KV[src * 64 + 4 * m];
            float k0 = __uint_as_float(kv.x << 16), v0 = __uint_as_float(kv.x & 0xffff0000u);
            float k1 = __uint_as_float(kv.y << 16), v1 = __uint_as_float(kv.y & 0xffff0000u);
            float k2 = __uint_as_float(kv.z << 16), v2 = __uint_as_float(kv.z & 0xffff0000u);
            float k3 = __uint_as_float(kv.w << 16), v3 = __uint_as_float(kv.w & 0xffff0000u);
            float tq = fmaf(q4.x, k0, fmaf(q4.y, k1, fmaf(q4.z, k2, q4.w * k3)));
            #pragma unroll
            for (int off = 1; off < C / 4; off <<= 1) tq += __shfl_xor(tq, off);
            float p = (esl < limit) ? __expf(tq) : 0.0f;
            ssum += p;
            acc0 = fmaf(p, v0, acc0);
            acc1 = fmaf(p, v1, acc1);
            acc2 = fmaf(p, v2, acc2);
            acc3 = fmaf(p, v3, acc3);
        }
    }

    // combine the 4 edge groups
    #pragma unroll
    for (int off = 16; off < 64; off <<= 1) {
        ssum += __shfl_xor(ssum, off);
        acc0 += __shfl_xor(acc0, off);
        acc1 += __shfl_xor(acc1, off);
        acc2 += __shfl_xor(acc2, off);
        acc3 += __shfl_xor(acc3, off);
    }

    float inv = 1.0f / (ssum + 1e-16f);
    float4 sv = *(const float4*)&S[n * 64 + 4 * m];
    float o0 = fmaf(acc0, inv, sv.x);
    float o1 = fmaf(acc1, inv, sv.y);
    float o2 = fmaf(acc2, inv, sv.z);
    float o3 = fmaf(acc3, inv, sv.w);

    // LayerNorm over 64 channels = 16 lanes x 4 (each group has all channels)
    float s = (o0 + o1) + (o2 + o3);
    #pragma unroll
    for (int off = 1; off < 16; off <<= 1) s += __shfl_xor(s, off);
    float mu = s * (1.0f / 64.0f);
    float d0 = o0 - mu, d1 = o1 - mu, d2 = o2 - mu, d3 = o3 - mu;
    float vs = (d0 * d0 + d1 * d1) + (d2 * d2 + d3 * d3);
    #pragma unroll
    for (int off = 1; off < 16; off <<= 1) vs += __shfl_xor(vs, off);
    float rstd = rsqrtf(vs * (1.0f / 64.0f) + 1e-5f);

    float4 gv = *(const float4*)&g[4 * m];
    float4 bv = *(const float4*)&b[4 * m];
    float y0 = d0 * rstd * gv.x + bv.x;
    float y1 = d1 * rstd * gv.y + bv.y;
    float y2 = d2 * rstd * gv.z + bv.z;
    float y3 = d3 * rstd * gv.w + bv.w;
    if (RES) {
        float4 rv = *(const float4*)&h_in[n * 64 + 4 * m];
        y0 = fmaf(0.1f, rv.x, y0);
        y1 = fmaf(0.1f, rv.y, y1);
        y2 = fmaf(0.1f, rv.z, y2);
        y3 = fmaf(0.1f, rv.w, y3);
    }
    if (RELU) {
        y0 = fmaxf(y0, 0.0f); y1 = fmaxf(y1, 0.0f);
        y2 = fmaxf(y2, 0.0f); y3 = fmaxf(y3, 0.0f);
    }
    if (grp == 0) {
        float4 yv = make_float4(y0, y1, y2, y3);
        *(float4*)&h_out[n * 64 + 4 * m] = yv;
    }
}

// ---------------------------------------------------------------------------
// Kernel: final two MLP heads. One wave per node.
__global__ void head_kernel(const float* __restrict__ h,
                            const float* __restrict__ Wr1, const float* __restrict__ br1,
                            const float* __restrict__ Wr2, const float* __restrict__ br2,
                            const float* __restrict__ Wt1, const float* __restrict__ bt1,
                            const float* __restrict__ Wt2, const float* __restrict__ bt2,
                            float* __restrict__ out) {
    __shared__ float sh[4][HID];
    int wave = threadIdx.x >> 6;
    int lane = threadIdx.x & 63;
    int n = blockIdx.x * 4 + wave;
    sh[wave][lane] = h[n * 64 + lane];
    __syncthreads();
    int half = lane >> 5;
    int j = lane & 31;
    const float* W1 = half ? Wt1 : Wr1;
    const float* b1 = half ? bt1 : br1;
    const float* W2 = half ? Wt2 : Wr2;
    const float* b2 = half ? bt2 : br2;
    float a = b1[j];
    #pragma unroll 8
    for (int i = 0; i < 64; i++) a = fmaf(sh[wave][i], W1[i * 32 + j], a);
    a = fmaxf(a, 0.0f);
    float r = a * W2[j];
    #pragma unroll
    for (int off = 1; off < 32; off <<= 1) r += __shfl_xor(r, off);
    if (j == 0) out[n * 2 + half] = r + b2[0];
}

// ---------------------------------------------------------------------------
extern "C" void kernel_launch(void* const* d_in, const int* in_sizes, int n_in,
                              void* d_out, int out_size, void* d_ws, size_t ws_size,
                              hipStream_t stream) {
    const float* x    = (const float*)d_in[0];
    const int*   ei   = (const int*)d_in[1];
    const int*   src  = ei;
    const int*   dst  = ei + N_EDGES;
    const float* ln0g = (const float*)d_in[2];
    const float* ln0b = (const float*)d_in[3];

    const float* P[27];
    for (int i = 0; i < 27; i++) P[i] = (const float*)d_in[4 + i];
    const float* Wr1 = (const float*)d_in[31];
    const float* br1 = (const float*)d_in[32];
    const float* Wr2 = (const float*)d_in[33];
    const float* br2 = (const float*)d_in[34];
    const float* Wt1 = (const float*)d_in[35];
    const float* bt1 = (const float*)d_in[36];
    const float* Wt2 = (const float*)d_in[37];
    const float* bt2 = (const float*)d_in[38];

    float* out = (float*)d_out;

    // workspace layout
    float* hbuf0 = (float*)d_ws;                 // N*64
    float* hbuf1 = hbuf0 + N_NODES * 64;         // N*64
    float* Qb    = hbuf1 + N_NODES * 64;         // N*64
    float* Sb    = Qb + N_NODES * 64;            // N*64
    unsigned int* KVb = (unsigned int*)(Sb + N_NODES * 64);   // N*64 uint
    int* row_ptr = (int*)(KVb + N_NODES * 64);   // N+1
    int* cursor  = row_ptr + (N_NODES + 1);      // N
    int* deg     = cursor + N_NODES;             // N
    int* colb    = deg + N_NODES;                // E
    int* csum    = colb + N_EDGES;               // N_CHUNKS
    int* coff    = csum + N_CHUNKS;              // N_CHUNKS

    // ---- graph structure (rebuilt every launch; ws is re-poisoned) ----
    zero_deg_kernel<<<N_CHUNKS, 256, 0, stream>>>(deg);
    ln0_kernel<<<6250, 256, 0, stream>>>(x, ln0g, ln0b, hbuf0);
    deg_kernel<<<(N_EDGES + 255) / 256, 256, 0, stream>>>(dst, deg);
    chunk_sum_kernel<<<N_CHUNKS, 256, 0, stream>>>(deg, csum);
    scan_sums_kernel<<<1, 64, 0, stream>>>(csum, coff, row_ptr);
    scan_final_kernel<<<N_CHUNKS, 256, 0, stream>>>(deg, coff, row_ptr, cursor);
    fill_kernel<<<(N_EDGES + 255) / 256, 256, 0, stream>>>(src, dst, cursor, colb);

    // ---- layer 0: 32 -> 64, heads=4, no residual, relu ----
    qkvs_kernel<32><<<N_QKVS_BLOCKS, 256, 0, stream>>>(hbuf0,
        P[0], P[1], P[2], P[3], P[4], P[5], P[6], Qb, KVb, Sb);
    agg_kernel<4, false, true><<<12500, 256, 0, stream>>>(Qb, KVb, Sb,
        row_ptr, colb, P[7], P[8], nullptr, hbuf1);

    // ---- layer 1: 64 -> 64, heads=4, residual, relu ----
    qkvs_kernel<64><<<N_QKVS_BLOCKS, 256, 0, stream>>>(hbuf1,
        P[9], P[10], P[11], P[12], P[13], P[14], P[15], Qb, KVb, Sb);
    agg_kernel<4, true, true><<<12500, 256, 0, stream>>>(Qb, KVb, Sb,
        row_ptr, colb, P[16], P[17], hbuf1, hbuf0);

    // ---- layer 2: 64 -> 64, heads=1, residual, no relu ----
    qkvs_kernel<64><<<N_QKVS_BLOCKS, 256, 0, stream>>>(hbuf0,
        P[18], P[19], P[20], P[21], P[22], P[23], P[24], Qb, KVb, Sb);
    agg_kernel<1, true, false><<<12500, 256, 0, stream>>>(Qb, KVb, Sb,
        row_ptr, colb, P[25], P[26], hbuf0, hbuf1);

    // ---- MLP heads ----
    head_kernel<<<12500, 256, 0, stream>>>(hbuf1,
        Wr1, br1, Wr2, br2, Wt1, bt1, Wt2, bt2, out);
}

// Round 8
// 419.651 us; speedup vs baseline: 1.5432x; 1.5432x over previous
//
#include <hip/hip_runtime.h>
#include <hip/hip_bf16.h>
#include <math.h>

#define N_NODES 50000
#define N_EDGES 800000
#define HID 64
#define N_CHUNKS ((N_NODES + 255) / 256)   // 196

typedef __attribute__((ext_vector_type(8))) short short8;
typedef __attribute__((ext_vector_type(4))) float float4v;

__device__ __forceinline__ unsigned short f32_to_bf16_rne(float f) {
    unsigned int u = __float_as_uint(f);
    unsigned int r = u + 0x7fffu + ((u >> 16) & 1u);
    return (unsigned short)(r >> 16);
}

// ---------------------------------------------------------------------------
// Kernel 1: initial LayerNorm over 32 features. One 32-lane half-wave per node.
__global__ void ln0_kernel(const float* __restrict__ x,
                           const float* __restrict__ g,
                           const float* __restrict__ b,
                           float* __restrict__ h0) {
    int lane = threadIdx.x & 63;
    int n = blockIdx.x * 8 + (threadIdx.x >> 6) * 2 + (lane >> 5);
    int c = lane & 31;
    float v = x[n * 32 + c];
    float s = v;
    #pragma unroll
    for (int off = 1; off < 32; off <<= 1) s += __shfl_xor(s, off);
    float mu = s * (1.0f / 32.0f);
    float d = v - mu;
    float vs = d * d;
    #pragma unroll
    for (int off = 1; off < 32; off <<= 1) vs += __shfl_xor(vs, off);
    float var = vs * (1.0f / 32.0f);
    float y = d * rsqrtf(var + 1e-5f) * g[c] + b[c];
    h0[n * 32 + c] = y;
}

// ---------------------------------------------------------------------------
// CSR build: zero, degree count, 3-phase hierarchical scan, scatter fill.
__global__ void zero_deg_kernel(int* __restrict__ deg) {
    int i = blockIdx.x * 256 + threadIdx.x;
    if (i < N_NODES) deg[i] = 0;
}

__global__ void deg_kernel(const int* __restrict__ dst, int* __restrict__ deg) {
    int e = blockIdx.x * blockDim.x + threadIdx.x;
    if (e >= N_EDGES) return;
    atomicAdd(&deg[dst[e]], 1);
}

__global__ void chunk_sum_kernel(const int* __restrict__ deg, int* __restrict__ csum) {
    int i = blockIdx.x * 256 + threadIdx.x;
    int v = (i < N_NODES) ? deg[i] : 0;
    #pragma unroll
    for (int off = 1; off < 64; off <<= 1) v += __shfl_xor(v, off);
    __shared__ int ws[4];
    if ((threadIdx.x & 63) == 0) ws[threadIdx.x >> 6] = v;
    __syncthreads();
    if (threadIdx.x == 0) csum[blockIdx.x] = ws[0] + ws[1] + ws[2] + ws[3];
}

__global__ void scan_sums_kernel(const int* __restrict__ csum,
                                 int* __restrict__ coff,
                                 int* __restrict__ row_ptr) {
    int lane = threadIdx.x;
    int carry = 0;
    for (int base = 0; base < N_CHUNKS; base += 64) {
        int i = base + lane;
        int v = (i < N_CHUNKS) ? csum[i] : 0;
        int incl = v;
        #pragma unroll
        for (int off = 1; off < 64; off <<= 1) {
            int t = __shfl_up(incl, off);
            if (lane >= off) incl += t;
        }
        if (i < N_CHUNKS) coff[i] = carry + incl - v;
        carry += __shfl(incl, 63);
    }
    if (lane == 0) row_ptr[N_NODES] = carry;
}

__global__ void scan_final_kernel(const int* __restrict__ deg,
                                  const int* __restrict__ coff,
                                  int* __restrict__ row_ptr,
                                  int* __restrict__ cursor) {
    int i = blockIdx.x * 256 + threadIdx.x;
    int lane = threadIdx.x & 63;
    int w = threadIdx.x >> 6;
    int v = (i < N_NODES) ? deg[i] : 0;
    int incl = v;
    #pragma unroll
    for (int off = 1; off < 64; off <<= 1) {
        int t = __shfl_up(incl, off);
        if (lane >= off) incl += t;
    }
    __shared__ int ws[4];
    if (lane == 63) ws[w] = incl;
    __syncthreads();
    int woff = 0;
    #pragma unroll
    for (int k = 0; k < 4; k++) if (k < w) woff += ws[k];
    int excl = coff[blockIdx.x] + woff + incl - v;
    if (i < N_NODES) { row_ptr[i] = excl; cursor[i] = excl; }
}

__global__ void fill_kernel(const int* __restrict__ src,
                            const int* __restrict__ dst,
                            int* __restrict__ cursor,
                            int* __restrict__ colb) {
    int e = blockIdx.x * blockDim.x + threadIdx.x;
    if (e >= N_EDGES) return;
    int d = dst[e];
    int pos = atomicAdd(&cursor[d], 1);
    colb[pos] = src[e];
}

// ---------------------------------------------------------------------------
// Weight prep: pack [Wq|Wk|Wv|Ws] (each Dx64 fp32) into bf16 B-fragment order
// for mfma_f32_16x16x32_bf16. Wp[((tile*KS+s)*64 + lane)*8 + j] = bf16(W[k][col])
// with k = s*32 + (lane>>4)*8 + j, col = (tile&3)*16 + (lane&15), matrix=tile>>2.
__global__ void wprep_kernel(const float* __restrict__ Wq, const float* __restrict__ Wk,
                             const float* __restrict__ Wv, const float* __restrict__ Ws,
                             int KS, unsigned short* __restrict__ Wp) {
    int idx = blockIdx.x * 256 + threadIdx.x;
    int total = 16 * KS * 512;
    if (idx >= total) return;
    int j = idx & 7;
    int lane = (idx >> 3) & 63;
    int ts = idx >> 9;            // tile*KS + s
    int s = ts % KS;
    int tile = ts / KS;
    int which = tile >> 2;
    int slice = tile & 3;
    int k = s * 32 + ((lane >> 4) * 8) + j;
    int col = slice * 16 + (lane & 15);
    const float* W = (which == 0) ? Wq : (which == 1) ? Wk : (which == 2) ? Wv : Ws;
    Wp[idx] = f32_to_bf16_rne(W[k * 64 + col]);
}

// ---------------------------------------------------------------------------
// Kernel: Q/K/V/Skip projections via MFMA. Block = 16 nodes; wave w owns the
// 16-col slice w of each of Q,K,V,S (tiles which*4+w). A-frag: h rows -> bf16.
// B-frag: prepped Wp, lane-contiguous 16B loads. fp32 accum; biases in fp32.
// K,V packed bf16: KV[n*64+c] = (bf16(V)<<16)|bf16(K).
template <int D>
__global__ __launch_bounds__(256) void qkvs_mfma_kernel(
        const float* __restrict__ h,
        const unsigned short* __restrict__ Wp,
        const float* __restrict__ bq, const float* __restrict__ bk,
        const float* __restrict__ bv,
        float* __restrict__ Q, unsigned int* __restrict__ KV,
        float* __restrict__ S) {
    constexpr int KS = D / 32;
    int t = threadIdx.x;
    int lane = t & 63;
    int w = t >> 6;
    int n0 = blockIdx.x * 16;
    int n16 = lane & 15;
    int quad = lane >> 4;
    int col = w * 16 + n16;

    // A fragments: A[m = lane&15][k = quad*8 + j]
    short8 afrag[KS];
    #pragma unroll
    for (int s = 0; s < KS; s++) {
        const float* hp = &h[(n0 + n16) * D + s * 32 + quad * 8];
        float4 a0 = *(const float4*)hp;
        float4 a1 = *(const float4*)(hp + 4);
        short8 af;
        af[0] = (short)f32_to_bf16_rne(a0.x);
        af[1] = (short)f32_to_bf16_rne(a0.y);
        af[2] = (short)f32_to_bf16_rne(a0.z);
        af[3] = (short)f32_to_bf16_rne(a0.w);
        af[4] = (short)f32_to_bf16_rne(a1.x);
        af[5] = (short)f32_to_bf16_rne(a1.y);
        af[6] = (short)f32_to_bf16_rne(a1.z);
        af[7] = (short)f32_to_bf16_rne(a1.w);
        afrag[s] = af;
    }

    float4v accs[4];
    #pragma unroll
    for (int which = 0; which < 4; which++) {
        float4v acc = {0.0f, 0.0f, 0.0f, 0.0f};
        int tile = which * 4 + w;
        #pragma unroll
        for (int s = 0; s < KS; s++) {
            short8 bfrag = *(const short8*)&Wp[((tile * KS + s) * 64 + lane) * 8];
            acc = __builtin_amdgcn_mfma_f32_16x16x32_bf16(afrag[s], bfrag, acc, 0, 0, 0);
        }
        accs[which] = acc;
    }

    float bqc = bq[col], bkc = bk[col], bvc = bv[col];

    // D layout: row = quad*4 + r, col = lane&15
    #pragma unroll
    for (int r = 0; r < 4; r++) {
        int node = n0 + quad * 4 + r;
        Q[node * 64 + col] = accs[0][r] + bqc;
        unsigned int kw = f32_to_bf16_rne(accs[1][r] + bkc);
        unsigned int vw = f32_to_bf16_rne(accs[2][r] + bvc);
        KV[node * 64 + col] = (vw << 16) | kw;
        S[node * 64 + col] = accs[3][r];
    }
}

// ---------------------------------------------------------------------------
// Kernel: per-node attention aggregation + skip + LayerNorm (+res/relu).
// One wave per node, 4 groups of 16 lanes; group streams its quarter of the
// edge list; lane covers 4 packed-bf16 channels (uint4 = whole 256 B KV row).
// No max-subtraction (scores O(3), exp fp32-safe; identical to ref softmax).
template <int HEADS, bool RES, bool RELU>
__global__ __launch_bounds__(256) void agg_kernel(
                           const float* __restrict__ Q, const unsigned int* __restrict__ KV,
                           const float* __restrict__ S,
                           const int* __restrict__ row_ptr, const int* __restrict__ colb,
                           const float* __restrict__ g, const float* __restrict__ b,
                           const float* __restrict__ h_in, float* __restrict__ h_out) {
    constexpr int C = HID / HEADS;
    int lane = threadIdx.x & 63;
    int m = lane & 15;      // sub-lane: channels 4m..4m+3
    int grp = lane >> 4;    // edge group 0..3
    int n = blockIdx.x * 4 + (threadIdx.x >> 6);

    const float scale = rsqrtf((float)C);
    float4 q4 = *(const float4*)&Q[n * 64 + 4 * m];
    q4.x *= scale; q4.y *= scale; q4.z *= scale; q4.w *= scale;

    int beg = row_ptr[n], end = row_ptr[n + 1];

    float ssum = 0.0f;
    float acc0 = 0.0f, acc1 = 0.0f, acc2 = 0.0f, acc3 = 0.0f;

    for (int base = beg; base < end; base += 64) {
        int limit = end - base;
        int src_l = (base + lane < end) ? colb[base + lane] : 0;
        int iters = (min(limit, 64) + 3) >> 2;
        #pragma unroll 4
        for (int jj = 0; jj < iters; jj++) {
            int esl = jj * 4 + grp;
            int src = __shfl(src_l, esl);
            uint4 kv = *(const uint4*)&KV[src * 64 + 4 * m];
            float k0 = __uint_as_float(kv.x << 16), v0 = __uint_as_float(kv.x & 0xffff0000u);
            float k1 = __uint_as_float(kv.y << 16), v1 = __uint_as_float(kv.y & 0xffff0000u);
            float k2 = __uint_as_float(kv.z << 16), v2 = __uint_as_float(kv.z & 0xffff0000u);
            float k3 = __uint_as_float(kv.w << 16), v3 = __uint_as_float(kv.w & 0xffff0000u);
            float tq = fmaf(q4.x, k0, fmaf(q4.y, k1, fmaf(q4.z, k2, q4.w * k3)));
            #pragma unroll
            for (int off = 1; off < C / 4; off <<= 1) tq += __shfl_xor(tq, off);
            float p = (esl < limit) ? __expf(tq) : 0.0f;
            ssum += p;
            acc0 = fmaf(p, v0, acc0);
            acc1 = fmaf(p, v1, acc1);
            acc2 = fmaf(p, v2, acc2);
            acc3 = fmaf(p, v3, acc3);
        }
    }

    #pragma unroll
    for (int off = 16; off < 64; off <<= 1) {
        ssum += __shfl_xor(ssum, off);
        acc0 += __shfl_xor(acc0, off);
        acc1 += __shfl_xor(acc1, off);
        acc2 += __shfl_xor(acc2, off);
        acc3 += __shfl_xor(acc3, off);
    }

    float inv = 1.0f / (ssum + 1e-16f);
    float4 sv = *(const float4*)&S[n * 64 + 4 * m];
    float o0 = fmaf(acc0, inv, sv.x);
    float o1 = fmaf(acc1, inv, sv.y);
    float o2 = fmaf(acc2, inv, sv.z);
    float o3 = fmaf(acc3, inv, sv.w);

    float s = (o0 + o1) + (o2 + o3);
    #pragma unroll
    for (int off = 1; off < 16; off <<= 1) s += __shfl_xor(s, off);
    float mu = s * (1.0f / 64.0f);
    float d0 = o0 - mu, d1 = o1 - mu, d2 = o2 - mu, d3 = o3 - mu;
    float vs = (d0 * d0 + d1 * d1) + (d2 * d2 + d3 * d3);
    #pragma unroll
    for (int off = 1; off < 16; off <<= 1) vs += __shfl_xor(vs, off);
    float rstd = rsqrtf(vs * (1.0f / 64.0f) + 1e-5f);

    float4 gv = *(const float4*)&g[4 * m];
    float4 bv = *(const float4*)&b[4 * m];
    float y0 = d0 * rstd * gv.x + bv.x;
    float y1 = d1 * rstd * gv.y + bv.y;
    float y2 = d2 * rstd * gv.z + bv.z;
    float y3 = d3 * rstd * gv.w + bv.w;
    if (RES) {
        float4 rv = *(const float4*)&h_in[n * 64 + 4 * m];
        y0 = fmaf(0.1f, rv.x, y0);
        y1 = fmaf(0.1f, rv.y, y1);
        y2 = fmaf(0.1f, rv.z, y2);
        y3 = fmaf(0.1f, rv.w, y3);
    }
    if (RELU) {
        y0 = fmaxf(y0, 0.0f); y1 = fmaxf(y1, 0.0f);
        y2 = fmaxf(y2, 0.0f); y3 = fmaxf(y3, 0.0f);
    }
    if (grp == 0) {
        float4 yv = make_float4(y0, y1, y2, y3);
        *(float4*)&h_out[n * 64 + 4 * m] = yv;
    }
}

// ---------------------------------------------------------------------------
// Kernel: final two MLP heads. One wave per node.
__global__ void head_kernel(const float* __restrict__ h,
                            const float* __restrict__ Wr1, const float* __restrict__ br1,
                            const float* __restrict__ Wr2, const float* __restrict__ br2,
                            const float* __restrict__ Wt1, const float* __restrict__ bt1,
                            const float* __restrict__ Wt2, const float* __restrict__ bt2,
                            float* __restrict__ out) {
    __shared__ float sh[4][HID];
    int wave = threadIdx.x >> 6;
    int lane = threadIdx.x & 63;
    int n = blockIdx.x * 4 + wave;
    sh[wave][lane] = h[n * 64 + lane];
    __syncthreads();
    int half = lane >> 5;
    int j = lane & 31;
    const float* W1 = half ? Wt1 : Wr1;
    const float* b1 = half ? bt1 : br1;
    const float* W2 = half ? Wt2 : Wr2;
    const float* b2 = half ? bt2 : br2;
    float a = b1[j];
    #pragma unroll 8
    for (int i = 0; i < 64; i++) a = fmaf(sh[wave][i], W1[i * 32 + j], a);
    a = fmaxf(a, 0.0f);
    float r = a * W2[j];
    #pragma unroll
    for (int off = 1; off < 32; off <<= 1) r += __shfl_xor(r, off);
    if (j == 0) out[n * 2 + half] = r + b2[0];
}

// ---------------------------------------------------------------------------
extern "C" void kernel_launch(void* const* d_in, const int* in_sizes, int n_in,
                              void* d_out, int out_size, void* d_ws, size_t ws_size,
                              hipStream_t stream) {
    const float* x    = (const float*)d_in[0];
    const int*   ei   = (const int*)d_in[1];
    const int*   src  = ei;
    const int*   dst  = ei + N_EDGES;
    const float* ln0g = (const float*)d_in[2];
    const float* ln0b = (const float*)d_in[3];

    const float* P[27];
    for (int i = 0; i < 27; i++) P[i] = (const float*)d_in[4 + i];
    const float* Wr1 = (const float*)d_in[31];
    const float* br1 = (const float*)d_in[32];
    const float* Wr2 = (const float*)d_in[33];
    const float* br2 = (const float*)d_in[34];
    const float* Wt1 = (const float*)d_in[35];
    const float* bt1 = (const float*)d_in[36];
    const float* Wt2 = (const float*)d_in[37];
    const float* bt2 = (const float*)d_in[38];

    float* out = (float*)d_out;

    // workspace layout
    float* hbuf0 = (float*)d_ws;                 // N*64
    float* hbuf1 = hbuf0 + N_NODES * 64;         // N*64
    float* Qb    = hbuf1 + N_NODES * 64;         // N*64
    float* Sb    = Qb + N_NODES * 64;            // N*64
    unsigned int* KVb = (unsigned int*)(Sb + N_NODES * 64);   // N*64 uint
    int* row_ptr = (int*)(KVb + N_NODES * 64);   // N+1
    int* cursor  = row_ptr + (N_NODES + 1);      // N
    int* deg     = cursor + N_NODES;             // N
    int* colb    = deg + N_NODES;                // E
    int* csum    = colb + N_EDGES;               // N_CHUNKS
    int* coff    = csum + N_CHUNKS;              // N_CHUNKS
    unsigned short* Wp0 = (unsigned short*)(coff + N_CHUNKS); // 16*1*512
    unsigned short* Wp1 = Wp0 + 16 * 1 * 512;                 // 16*2*512
    unsigned short* Wp2 = Wp1 + 16 * 2 * 512;                 // 16*2*512

    // ---- graph structure + weight prep (rebuilt every launch) ----
    zero_deg_kernel<<<N_CHUNKS, 256, 0, stream>>>(deg);
    ln0_kernel<<<6250, 256, 0, stream>>>(x, ln0g, ln0b, hbuf0);
    deg_kernel<<<(N_EDGES + 255) / 256, 256, 0, stream>>>(dst, deg);
    chunk_sum_kernel<<<N_CHUNKS, 256, 0, stream>>>(deg, csum);
    scan_sums_kernel<<<1, 64, 0, stream>>>(csum, coff, row_ptr);
    scan_final_kernel<<<N_CHUNKS, 256, 0, stream>>>(deg, coff, row_ptr, cursor);
    fill_kernel<<<(N_EDGES + 255) / 256, 256, 0, stream>>>(src, dst, cursor, colb);
    wprep_kernel<<<32, 256, 0, stream>>>(P[0],  P[2],  P[4],  P[6],  1, Wp0);
    wprep_kernel<<<64, 256, 0, stream>>>(P[9],  P[11], P[13], P[15], 2, Wp1);
    wprep_kernel<<<64, 256, 0, stream>>>(P[18], P[20], P[22], P[24], 2, Wp2);

    // ---- layer 0: 32 -> 64, heads=4, no residual, relu ----
    qkvs_mfma_kernel<32><<<3125, 256, 0, stream>>>(hbuf0, Wp0,
        P[1], P[3], P[5], Qb, KVb, Sb);
    agg_kernel<4, false, true><<<12500, 256, 0, stream>>>(Qb, KVb, Sb,
        row_ptr, colb, P[7], P[8], nullptr, hbuf1);

    // ---- layer 1: 64 -> 64, heads=4, residual, relu ----
    qkvs_mfma_kernel<64><<<3125, 256, 0, stream>>>(hbuf1, Wp1,
        P[10], P[12], P[14], Qb, KVb, Sb);
    agg_kernel<4, true, true><<<12500, 256, 0, stream>>>(Qb, KVb, Sb,
        row_ptr, colb, P[16], P[17], hbuf1, hbuf0);

    // ---- layer 2: 64 -> 64, heads=1, residual, no relu ----
    qkvs_mfma_kernel<64><<<3125, 256, 0, stream>>>(hbuf0, Wp2,
        P[19], P[21], P[23], Qb, KVb, Sb);
    agg_kernel<1, true, false><<<12500, 256, 0, stream>>>(Qb, KVb, Sb,
        row_ptr, colb, P[25], P[26], hbuf0, hbuf1);

    // ---- MLP heads ----
    head_kernel<<<12500, 256, 0, stream>>>(hbuf1,
        Wr1, br1, Wr2, br2, Wt1, bt1, Wt2, bt2, out);
}